// Round 2
// baseline (743.934 us; speedup 1.0000x reference)
//
#include <hip/hip_runtime.h>
#include <cstdint>

// ViMBlock bf16-MFMA + chunked parallel scan. B=4, L=4096, D=1024, N=64, K=3.
// R6: 256x256 8-phase GEMM template (T1 xcd-swizzle + T2 LDS swizzle +
// T3/T4 counted vmcnt(6) never-drain + T5 setprio) for the big GEMMs.
// LDS 128KiB dbuf, 512 thr (8 waves 2Mx4N), BK=64, 16 MFMA/phase,
// stage-freed-regions schedule, vmcnt(6) only at phases 4/8.
// u-proj (N=128) stays on the old 128^2 kernel.

#define L_SEQ 4096
#define D_DIM 1024
#define B_SZ 4
#define M_TOK (B_SZ * L_SEQ)   // 16384 tokens
#define CHUNKS 64
#define CLEN (L_SEQ / CHUNKS)  // 64

typedef short bf16x8 __attribute__((ext_vector_type(8)));
typedef float floatx4 __attribute__((ext_vector_type(4)));

__device__ inline unsigned short f2bf(float f) {
  union { float f; unsigned int u; } v; v.f = f;
  unsigned int r = v.u + 0x7FFFu + ((v.u >> 16) & 1u);
  return (unsigned short)(r >> 16);
}
__device__ inline float bf2f(unsigned short h) {
  union { unsigned int u; float f; } v; v.u = ((unsigned int)h) << 16;
  return v.f;
}

__device__ inline void load_lds16(const unsigned short* g, unsigned short* l) {
  __builtin_amdgcn_global_load_lds(
      (const __attribute__((address_space(1))) unsigned int*)g,
      (__attribute__((address_space(3))) unsigned int*)l, 16, 0, 0);
}

// ---------------- RMSNorm: fp32 in -> bf16 out ----------------
__global__ __launch_bounds__(256) void rmsnorm_kernel(
    const float* __restrict__ T, const float* __restrict__ scale,
    unsigned short* __restrict__ Tn) {
  int tok = blockIdx.x;
  int t = threadIdx.x;
  const float4* row = (const float4*)(T + (size_t)tok * D_DIM);
  float4 v = row[t];
  float ss = v.x*v.x + v.y*v.y + v.z*v.z + v.w*v.w;
  #pragma unroll
  for (int off = 32; off > 0; off >>= 1) ss += __shfl_down(ss, off);
  __shared__ float part[4];
  if ((t & 63) == 0) part[t >> 6] = ss;
  __syncthreads();
  float total = part[0] + part[1] + part[2] + part[3];
  float rinv = rsqrtf(total * (1.0f / D_DIM) + 1e-6f);
  const float4* sc4 = (const float4*)scale;
  float4 s = sc4[t];
  ushort4 o;
  o.x = f2bf(v.x * rinv * s.x); o.y = f2bf(v.y * rinv * s.y);
  o.z = f2bf(v.z * rinv * s.z); o.w = f2bf(v.w * rinv * s.w);
  ((ushort4*)(Tn + (size_t)tok * D_DIM))[t] = o;
}

// ---------------- fp32 -> bf16 convert ----------------
__global__ __launch_bounds__(256) void f2bf_vec_kernel(
    const float* __restrict__ in, unsigned short* __restrict__ out, int n4) {
  int i = blockIdx.x * 256 + threadIdx.x;
  if (i < n4) {
    float4 v = ((const float4*)in)[i];
    ushort4 o; o.x = f2bf(v.x); o.y = f2bf(v.y); o.z = f2bf(v.z); o.w = f2bf(v.w);
    ((ushort4*)out)[i] = o;
  }
}

// ---------------- prepack SSM weights -> bf16 ----------------
__global__ void prepack_kernel(
    const float* __restrict__ f_win, const float* __restrict__ b_win,
    const float* __restrict__ f_wout, const float* __restrict__ b_wout,
    unsigned short* __restrict__ Wu, unsigned short* __restrict__ Wy) {
  int i = blockIdx.x * blockDim.x + threadIdx.x;
  if (i < 128 * D_DIM) {
    int n = i >> 10, k = i & (D_DIM - 1);
    Wu[i] = f2bf((n < 64) ? f_win[n * D_DIM + k] : b_win[(n - 64) * D_DIM + k]);
    int d = i >> 7, kk = i & 127;
    Wy[i] = f2bf((kk < 64) ? f_wout[d * 64 + kk] : b_wout[d * 64 + (kk - 64)]);
  }
}

// ================= 256x256 8-phase MFMA GEMM: C = A @ Bw^T =================
// 512 threads = 8 waves, wave grid 2(M) x 4(N); per-wave 128x64 output
// (acc[8][4] f32x4). LDS: dbuf x [256][64] bf16 per operand = 128 KiB.
// LDS swizzle: element (row r, k-chunk c) stored at 16B-slot ((c + r) & 7)
// within its row; linear gload_lds dest with pre-permuted per-lane global
// source (collapses to per-lane constant since chunks are 8-row aligned);
// same perm applied on ds_read addresses -> conflict-free b128 reads.
// Phase schedule per iter (2 K-tiles: buf0 = 2i, buf1 = 2i+1):
//   half0 ph0..3 = (h,ks) (0,0)(1,0)(0,1)(1,1) on buf0; half1 same on buf1.
//   stages: h0ph0: buf1 A-h1 (tile 2i+1);  h0ph3: buf0 A-h0 + B (tile 2i+2);
//           h1ph0: buf0 A-h1 (2i+2);       h1ph3: buf1 A-h0 + B (2i+3).
//   vmcnt(6) at h0ph3 / h1ph3 (counted, never 0 mid-loop); 2 s_barrier/phase.
// MODE semantics identical to gemm_mfma_kernel.
template<int MODE, typename OUT_T>
__global__ __launch_bounds__(512, 2) void gemm256_kernel(
    const unsigned short* __restrict__ A, const unsigned short* __restrict__ Bw,
    const float* __restrict__ bias, OUT_T* __restrict__ out,
    int M, int N, int Kt,
    const void* __restrict__ aux0, unsigned short* __restrict__ aux1) {
  __shared__ __align__(16) unsigned short As2[2][256 * 64];
  __shared__ __align__(16) unsigned short Bs2[2][256 * 64];
  const int tid = threadIdx.x;
  const int w = tid >> 6, lane = tid & 63;
  const int quad = lane >> 4, lrow = lane & 15;
  const int wm = w >> 2, wn = w & 3;

  // T1: XCD-aware chunked swizzle (launch shapes guarantee nwg % 8 == 0)
  const int nx = N >> 8;
  const int nwg = nx * (M >> 8);
  int obid = blockIdx.y * nx + blockIdx.x;
  int swz = (nwg & 7) ? obid : ((obid & 7) * (nwg >> 3) + (obid >> 3));
  const int bm = (swz / nx) << 8;
  const int bn = (swz % nx) << 8;

  // per-lane stage source offset (elements): inverse LDS-slot permutation.
  // lane covers physical slot (lr, ls) of its 1KB chunk -> logical k-chunk
  // c = (ls - lr) & 7 (chunk row starts are 8-aligned).
  const int lr = lane >> 3, ls = lane & 7;
  const int laneOff = lr * Kt + (((ls - lr) & 7) << 3);
  const unsigned short* Asrc = A + (size_t)bm * Kt + laneOff;
  const unsigned short* Bsrc = Bw + (size_t)bn * Kt + laneOff;

  floatx4 acc[8][4] = {};

  const int nkt = Kt >> 6;      // # K-tiles of 64
  const int nIter = nkt >> 1;   // 2 K-tiles per iteration

  auto stageA = [&](int buf, int h, int kt) {
    int t0 = h * 64 + w * 8;
    int t1 = 128 + h * 64 + w * 8;
    load_lds16(Asrc + (size_t)t0 * Kt + kt * 64, &As2[buf][t0 * 64]);
    load_lds16(Asrc + (size_t)t1 * Kt + kt * 64, &As2[buf][t1 * 64]);
  };
  auto stageB = [&](int buf, int kt) {
    #pragma unroll
    for (int j = 0; j < 4; ++j) {
      int t0 = j * 64 + w * 8;
      load_lds16(Bsrc + (size_t)t0 * Kt + kt * 64, &Bs2[buf][t0 * 64]);
    }
  };
  // fragment LDS address (elements): row r, k-half ks, this lane's quad
  auto fragAddr = [&](int r, int ks) {
    return (r << 6) + ((((ks << 2) + quad + r) & 7) << 3);
  };

  // prologue: buf0 = K-tile 0 full (8 loads), buf1 = K-tile 1 A-h0 + B (6)
  stageA(0, 0, 0); stageB(0, 0); stageA(0, 1, 0);
  stageA(1, 0, 1); stageB(1, 1);
  asm volatile("s_waitcnt vmcnt(6)" ::: "memory");
  __builtin_amdgcn_s_barrier();

  const int rA0 = wm * 128 + lrow;
  const int rB0 = wn * 64 + lrow;

  for (int i = 0; i < nIter; ++i) {
    const int t2 = 2 * i + 2, t3 = 2 * i + 3;
    const bool s2 = t2 < nkt, s3 = t3 < nkt;
    bf16x8 af[4], bfr[4];

    #pragma unroll
    for (int half = 0; half < 2; ++half) {
      const unsigned short* Ab = As2[half];
      const unsigned short* Bb = Bs2[half];
      #pragma unroll
      for (int ph = 0; ph < 4; ++ph) {
        const int h = ph & 1, ks = ph >> 1;
        // ds reads for this phase (B held in regs across the h=0/h=1 pair)
        if (h == 0) {
          #pragma unroll
          for (int ni = 0; ni < 4; ++ni)
            bfr[ni] = *(const bf16x8*)(Bb + fragAddr(rB0 + ni * 16, ks));
        }
        #pragma unroll
        for (int mi = 0; mi < 4; ++mi)
          af[mi] = *(const bf16x8*)(Ab + fragAddr(rA0 + h * 64 + mi * 16, ks));
        // stage issues (into regions freed by the previous phase)
        if (half == 0) {
          if (ph == 0) stageA(1, 1, 2 * i + 1);
          if (ph == 3 && s2) { stageA(0, 0, t2); stageB(0, t2); }
        } else {
          if (ph == 0 && s2) stageA(0, 1, t2);
          if (ph == 3 && s3) { stageA(1, 0, t3); stageB(1, t3); }
        }
        // counted waits at phase 4 / phase 8 only
        if (ph == 3) {
          if ((half == 0) ? s2 : s3)
            asm volatile("s_waitcnt vmcnt(6)" ::: "memory");
          else
            asm volatile("s_waitcnt vmcnt(0)" ::: "memory");
        }
        __builtin_amdgcn_s_barrier();
        asm volatile("s_waitcnt lgkmcnt(0)" ::: "memory");
        __builtin_amdgcn_sched_barrier(0);
        __builtin_amdgcn_s_setprio(1);
        #pragma unroll
        for (int mi = 0; mi < 4; ++mi)
          #pragma unroll
          for (int ni = 0; ni < 4; ++ni)
            acc[h * 4 + mi][ni] = __builtin_amdgcn_mfma_f32_16x16x32_bf16(
                af[mi], bfr[ni], acc[h * 4 + mi][ni], 0, 0, 0);
        __builtin_amdgcn_s_setprio(0);
        __builtin_amdgcn_s_barrier();
      }
    }
  }

  // epilogue: C/D layout col=lane&15, row=quad*4+reg  [m89-verified]
  #pragma unroll
  for (int mi8 = 0; mi8 < 8; ++mi8) {
    #pragma unroll
    for (int ni = 0; ni < 4; ++ni) {
      #pragma unroll
      for (int r = 0; r < 4; ++r) {
        int m = bm + wm * 128 + mi8 * 16 + quad * 4 + r;
        int n = bn + wn * 64 + ni * 16 + lrow;
        float v = acc[mi8][ni][r];
        if (MODE == 0) {
          if (bias) v += bias[n];
          if (sizeof(OUT_T) == 2) out[(size_t)m * N + n] = (OUT_T)f2bf(v);
          else                    out[(size_t)m * N + n] = (OUT_T)v;
        } else if (MODE == 1) {
          if (bias) v += bias[n];
          if (n < D_DIM) ((unsigned short*)out)[(size_t)m * D_DIM + n] = f2bf(v);
          else aux1[(size_t)m * D_DIM + (n - D_DIM)] = f2bf(1.0f / (1.0f + expf(-v)));
        } else if (MODE == 2) {
          v *= bf2f(((const unsigned short*)aux0)[(size_t)m * N + n]);
          ((unsigned short*)out)[(size_t)m * N + n] = f2bf(v);
        } else {
          if (bias) v += bias[n];
          v += ((const float*)aux0)[(size_t)m * N + n];
          ((float*)out)[(size_t)m * N + n] = v;
        }
      }
    }
  }
}

// ---------------- 128x128 2-phase GEMM (kept for N=128 u-proj) ----------------
template<int MODE, typename OUT_T>
__global__ __launch_bounds__(256) void gemm_mfma_kernel(
    const unsigned short* __restrict__ A, const unsigned short* __restrict__ Bw,
    const float* __restrict__ bias, OUT_T* __restrict__ out,
    int M, int N, int Kt,
    const void* __restrict__ aux0, unsigned short* __restrict__ aux1) {
  __shared__ unsigned short As[2][128 * 32];
  __shared__ unsigned short Bs[2][128 * 32];
  int tid = threadIdx.x;
  int wave = tid >> 6, lane = tid & 63;
  int quad = lane >> 4, lrow = lane & 15;
  int bm = blockIdx.y * 128, bn = blockIdx.x * 128;
  int wm = (wave & 1) * 64, wn = (wave >> 1) * 64;

  int r0 = tid >> 2;
  int c8 = (tid & 3) * 8;
  const unsigned short* Ag0 = A  + (size_t)(bm + r0) * Kt + c8;
  const unsigned short* Ag1 = A  + (size_t)(bm + 64 + r0) * Kt + c8;
  const unsigned short* Bg0 = Bw + (size_t)(bn + r0) * Kt + c8;
  const unsigned short* Bg1 = Bw + (size_t)(bn + 64 + r0) * Kt + c8;
  int woff = wave * 512;

  floatx4 acc[4][4] = {};
  int nt = Kt >> 5;

  load_lds16(Ag0, &As[0][0] + woff);
  load_lds16(Ag1, &As[0][0] + 2048 + woff);
  load_lds16(Bg0, &Bs[0][0] + woff);
  load_lds16(Bg1, &Bs[0][0] + 2048 + woff);
  __syncthreads();

  int cur = 0;
  for (int t = 0; t < nt; ++t) {
    if (t + 1 < nt) {
      int k0 = (t + 1) << 5;
      int nb = cur ^ 1;
      load_lds16(Ag0 + k0, &As[nb][0] + woff);
      load_lds16(Ag1 + k0, &As[nb][0] + 2048 + woff);
      load_lds16(Bg0 + k0, &Bs[nb][0] + woff);
      load_lds16(Bg1 + k0, &Bs[nb][0] + 2048 + woff);
    }
    {
      const unsigned short* Ab = &As[cur][0];
      const unsigned short* Bb = &Bs[cur][0];
      bf16x8 af[4], bfr[4];
      #pragma unroll
      for (int mi = 0; mi < 4; ++mi)
        af[mi] = *(const bf16x8*)(Ab + (wm + mi * 16 + lrow) * 32 + quad * 8);
      #pragma unroll
      for (int ni = 0; ni < 4; ++ni)
        bfr[ni] = *(const bf16x8*)(Bb + (wn + ni * 16 + lrow) * 32 + quad * 8);
      __builtin_amdgcn_s_setprio(1);
      #pragma unroll
      for (int mi = 0; mi < 4; ++mi)
        #pragma unroll
        for (int ni = 0; ni < 4; ++ni)
          acc[mi][ni] = __builtin_amdgcn_mfma_f32_16x16x32_bf16(
              af[mi], bfr[ni], acc[mi][ni], 0, 0, 0);
      __builtin_amdgcn_s_setprio(0);
    }
    if (t + 1 < nt) {
      __syncthreads();
      cur ^= 1;
    }
  }

  #pragma unroll
  for (int mi = 0; mi < 4; ++mi) {
    #pragma unroll
    for (int ni = 0; ni < 4; ++ni) {
      #pragma unroll
      for (int r = 0; r < 4; ++r) {
        int m = bm + wm + mi * 16 + quad * 4 + r;
        int n = bn + wn + ni * 16 + lrow;
        float v = acc[mi][ni][r];
        if (MODE == 0) {
          if (bias) v += bias[n];
          if (sizeof(OUT_T) == 2) out[(size_t)m * N + n] = (OUT_T)f2bf(v);
          else                    out[(size_t)m * N + n] = (OUT_T)v;
        } else if (MODE == 1) {
          if (bias) v += bias[n];
          if (n < D_DIM) ((unsigned short*)out)[(size_t)m * D_DIM + n] = f2bf(v);
          else aux1[(size_t)m * D_DIM + (n - D_DIM)] = f2bf(1.0f / (1.0f + expf(-v)));
        } else if (MODE == 2) {
          v *= bf2f(((const unsigned short*)aux0)[(size_t)m * N + n]);
          ((unsigned short*)out)[(size_t)m * N + n] = f2bf(v);
        } else {
          if (bias) v += bias[n];
          v += ((const float*)aux0)[(size_t)m * N + n];
          ((float*)out)[(size_t)m * N + n] = v;
        }
      }
    }
  }
}

// ---------------- depthwise conv1d K=3 ----------------
__global__ __launch_bounds__(256) void dwconv_kernel(
    const unsigned short* __restrict__ x, const float* __restrict__ w,
    const float* __restrict__ b, unsigned short* __restrict__ out) {
  size_t i8 = (size_t)blockIdx.x * 256 + threadIdx.x;
  int d8 = (int)(i8 & (D_DIM / 8 - 1));
  size_t tok = i8 >> 7;
  int l = (int)(tok & (L_SEQ - 1));
  int d0 = d8 * 8;
  size_t base = tok * D_DIM + d0;
  bf16x8 cur = *(const bf16x8*)(x + base);
  float acc[8];
  #pragma unroll
  for (int j = 0; j < 8; ++j) {
    int d = d0 + j;
    acc[j] = b[d] + w[d * 3 + 1] * bf2f((unsigned short)cur[j]);
  }
  if (l > 0) {
    bf16x8 prv = *(const bf16x8*)(x + base - D_DIM);
    #pragma unroll
    for (int j = 0; j < 8; ++j) acc[j] += w[(d0 + j) * 3 + 0] * bf2f((unsigned short)prv[j]);
  }
  if (l < L_SEQ - 1) {
    bf16x8 nxt = *(const bf16x8*)(x + base + D_DIM);
    #pragma unroll
    for (int j = 0; j < 8; ++j) acc[j] += w[(d0 + j) * 3 + 2] * bf2f((unsigned short)nxt[j]);
  }
  bf16x8 o;
  #pragma unroll
  for (int j = 0; j < 8; ++j) o[j] = (short)f2bf(acc[j]);
  *(bf16x8*)(out + base) = o;
}

// ---------------- SSM params helper ----------------
__device__ inline void ssm_params(
    int col,
    const float* f_logA, const float* f_B, const float* f_C, const float* f_logdt,
    const float* b_logA, const float* b_B, const float* b_C, const float* b_logdt,
    float& Abar, float& Bbar, float& Cc, float& Aa, float& dt) {
  int dir = col >> 6, n = col & 63;
  const float* logA  = dir ? b_logA  : f_logA;
  const float* Bp    = dir ? b_B     : f_B;
  const float* Cp    = dir ? b_C     : f_C;
  const float* logdt = dir ? b_logdt : f_logdt;
  dt = expf(logdt[0]);
  Aa = -expf(logA[n]);
  Abar = expf(Aa * dt);
  float frac = (fabsf(Aa) < 1e-6f) ? dt : (Abar - 1.0f) / Aa;
  Bbar = frac * Bp[n];
  Cc = Cp[n];
}

// ---------------- scan S1: per-chunk local end-states ----------------
__global__ __launch_bounds__(128) void scan_s1_kernel(
    const float* __restrict__ u, float* __restrict__ states,
    const float* __restrict__ f_logA, const float* __restrict__ f_B,
    const float* __restrict__ f_C, const float* __restrict__ f_logdt,
    const float* __restrict__ b_logA, const float* __restrict__ b_B,
    const float* __restrict__ b_C, const float* __restrict__ b_logdt) {
  int col = threadIdx.x;
  int chunk = blockIdx.x, b = blockIdx.y;
  float Abar, Bbar, Cc, Aa, dt;
  ssm_params(col, f_logA, f_B, f_C, f_logdt, b_logA, b_B, b_C, b_logdt,
             Abar, Bbar, Cc, Aa, dt);
  size_t base = ((size_t)b * L_SEQ + (size_t)chunk * CLEN) * 128 + col;
  float h = 0.0f;
  if (col < 64) {
    for (int i0 = 0; i0 < CLEN; i0 += 8) {
      float uv[8];
      #pragma unroll
      for (int j = 0; j < 8; ++j) uv[j] = u[base + (size_t)(i0 + j) * 128];
      #pragma unroll
      for (int j = 0; j < 8; ++j) h = h * Abar + uv[j] * Bbar;
    }
  } else {
    for (int i0 = CLEN - 1; i0 >= 0; i0 -= 8) {
      float uv[8];
      #pragma unroll
      for (int j = 0; j < 8; ++j) uv[j] = u[base + (size_t)(i0 - j) * 128];
      #pragma unroll
      for (int j = 0; j < 8; ++j) h = h * Abar + uv[j] * Bbar;
    }
  }
  states[((size_t)b * CHUNKS + chunk) * 128 + col] = h;
}

// ---------------- scan S2: carries across chunks ----------------
__global__ __launch_bounds__(512) void scan_s2_kernel(
    const float* __restrict__ states, float* __restrict__ carries,
    const float* __restrict__ f_logA, const float* __restrict__ f_B,
    const float* __restrict__ f_C, const float* __restrict__ f_logdt,
    const float* __restrict__ b_logA, const float* __restrict__ b_B,
    const float* __restrict__ b_C, const float* __restrict__ b_logdt) {
  int tid = threadIdx.x;
  int b = tid >> 7, col = tid & 127;
  float Abar, Bbar, Cc, Aa, dt;
  ssm_params(col, f_logA, f_B, f_C, f_logdt, b_logA, b_B, b_C, b_logdt,
             Abar, Bbar, Cc, Aa, dt);
  float Ac = expf(Aa * dt * (float)CLEN);   // Abar^CLEN
  size_t sb = (size_t)b * CHUNKS * 128 + col;
  float cur = 0.0f;
  if (col < 64) {
    for (int c = 0; c < CHUNKS; ++c) {
      carries[sb + (size_t)c * 128] = cur;
      cur = cur * Ac + states[sb + (size_t)c * 128];
    }
  } else {
    for (int c = CHUNKS - 1; c >= 0; --c) {
      carries[sb + (size_t)c * 128] = cur;
      cur = cur * Ac + states[sb + (size_t)c * 128];
    }
  }
}

// ---------------- scan S3: re-scan with carry, write y (bf16) ----------------
__global__ __launch_bounds__(128) void scan_s3_kernel(
    const float* __restrict__ u, const float* __restrict__ carries,
    unsigned short* __restrict__ y,
    const float* __restrict__ f_logA, const float* __restrict__ f_B,
    const float* __restrict__ f_C, const float* __restrict__ f_logdt,
    const float* __restrict__ b_logA, const float* __restrict__ b_B,
    const float* __restrict__ b_C, const float* __restrict__ b_logdt) {
  int col = threadIdx.x;
  int chunk = blockIdx.x, b = blockIdx.y;
  float Abar, Bbar, Cc, Aa, dt;
  ssm_params(col, f_logA, f_B, f_C, f_logdt, b_logA, b_B, b_C, b_logdt,
             Abar, Bbar, Cc, Aa, dt);
  size_t base = ((size_t)b * L_SEQ + (size_t)chunk * CLEN) * 128 + col;
  float h = carries[((size_t)b * CHUNKS + chunk) * 128 + col];
  if (col < 64) {
    for (int i0 = 0; i0 < CLEN; i0 += 8) {
      float uv[8];
      #pragma unroll
      for (int j = 0; j < 8; ++j) uv[j] = u[base + (size_t)(i0 + j) * 128];
      #pragma unroll
      for (int j = 0; j < 8; ++j) {
        h = h * Abar + uv[j] * Bbar;
        y[base + (size_t)(i0 + j) * 128] = f2bf(h * Cc);
      }
    }
  } else {
    for (int i0 = CLEN - 1; i0 >= 0; i0 -= 8) {
      float uv[8];
      #pragma unroll
      for (int j = 0; j < 8; ++j) uv[j] = u[base + (size_t)(i0 - j) * 128];
      #pragma unroll
      for (int j = 0; j < 8; ++j) {
        h = h * Abar + uv[j] * Bbar;
        y[base + (size_t)(i0 - j) * 128] = f2bf(h * Cc);
      }
    }
  }
}

extern "C" void kernel_launch(void* const* d_in, const int* in_sizes, int n_in,
                              void* d_out, int out_size, void* d_ws, size_t ws_size,
                              hipStream_t stream) {
  const float* T         = (const float*)d_in[0];
  const float* norm_scale= (const float*)d_in[1];
  const float* in_w      = (const float*)d_in[2];
  const float* in_b      = (const float*)d_in[3];
  const float* dw_w      = (const float*)d_in[4];
  const float* dw_b      = (const float*)d_in[5];
  const float* pw_w      = (const float*)d_in[6];
  const float* pw_b      = (const float*)d_in[7];
  const float* f_win     = (const float*)d_in[8];
  const float* f_wout    = (const float*)d_in[9];
  const float* f_logA    = (const float*)d_in[10];
  const float* f_B       = (const float*)d_in[11];
  const float* f_C       = (const float*)d_in[12];
  const float* f_logdt   = (const float*)d_in[13];
  const float* b_win     = (const float*)d_in[14];
  const float* b_wout    = (const float*)d_in[15];
  const float* b_logA    = (const float*)d_in[16];
  const float* b_B       = (const float*)d_in[17];
  const float* b_C       = (const float*)d_in[18];
  const float* b_logdt   = (const float*)d_in[19];
  const float* out_w     = (const float*)d_in[20];
  const float* out_b     = (const float*)d_in[21];
  float* out = (float*)d_out;

  char* ws = (char*)d_ws;
  const size_t MD = (size_t)M_TOK * D_DIM;
  unsigned short* gate  = (unsigned short*)ws;              ws += MD * 2;
  unsigned short* bufA  = (unsigned short*)ws;              ws += MD * 2;
  unsigned short* bufB  = (unsigned short*)ws;              ws += MD * 2;
  float*          u     = (float*)ws;                       ws += (size_t)M_TOK * 128 * 4;
  unsigned short* ybuf  = (unsigned short*)ws;              ws += (size_t)M_TOK * 128 * 2;
  unsigned short* w_in  = (unsigned short*)ws;              ws += (size_t)2 * D_DIM * D_DIM * 2;
  unsigned short* w_pw  = (unsigned short*)ws;              ws += (size_t)D_DIM * D_DIM * 2;
  unsigned short* w_out = (unsigned short*)ws;              ws += (size_t)D_DIM * D_DIM * 2;
  unsigned short* Wu    = (unsigned short*)ws;              ws += (size_t)128 * D_DIM * 2;
  unsigned short* Wy    = (unsigned short*)ws;              ws += (size_t)128 * D_DIM * 2;
  float*          states= (float*)ws;                       ws += (size_t)B_SZ * CHUNKS * 128 * 4;
  float*          carries=(float*)ws;

  // 0. weight conversion / prepack
  f2bf_vec_kernel<<<(2 * D_DIM * D_DIM / 4 + 255) / 256, 256, 0, stream>>>(in_w, w_in, 2 * D_DIM * D_DIM / 4);
  f2bf_vec_kernel<<<(D_DIM * D_DIM / 4 + 255) / 256, 256, 0, stream>>>(pw_w, w_pw, D_DIM * D_DIM / 4);
  f2bf_vec_kernel<<<(D_DIM * D_DIM / 4 + 255) / 256, 256, 0, stream>>>(out_w, w_out, D_DIM * D_DIM / 4);
  prepack_kernel<<<(128 * D_DIM) / 256, 256, 0, stream>>>(f_win, b_win, f_wout, b_wout, Wu, Wy);
  // 1. RMSNorm: T -> bufA (bf16)
  rmsnorm_kernel<<<M_TOK, 256, 0, stream>>>(T, norm_scale, bufA);
  // 2. in_linear: bufA @ w_in^T + in_b -> x(bufB bf16), gate(bf16)
  {
    dim3 g((2 * D_DIM) / 256, M_TOK / 256);
    gemm256_kernel<1, unsigned short><<<g, 512, 0, stream>>>(
        bufA, w_in, in_b, bufB, M_TOK, 2 * D_DIM, D_DIM, nullptr, gate);
  }
  // 3. depthwise conv: bufB -> bufA
  dwconv_kernel<<<(MD / 8) / 256, 256, 0, stream>>>(bufB, dw_w, dw_b, bufA);
  // 4. pointwise: bufA @ w_pw^T + pw_b -> bufB (x_conv bf16)
  {
    dim3 g(D_DIM / 256, M_TOK / 256);
    gemm256_kernel<0, unsigned short><<<g, 512, 0, stream>>>(
        bufA, w_pw, pw_b, bufB, M_TOK, D_DIM, D_DIM, nullptr, nullptr);
  }
  // 5. SSM in-proj: bufB @ Wu^T -> u (f32, M x 128)  [old 128^2 kernel]
  {
    dim3 g(1, M_TOK / 128);
    gemm_mfma_kernel<0, float><<<g, 256, 0, stream>>>(
        bufB, Wu, nullptr, u, M_TOK, 128, D_DIM, nullptr, nullptr);
  }
  // 6. chunked bidirectional scan: u -> ybuf (bf16)
  {
    dim3 g1(CHUNKS, B_SZ);
    scan_s1_kernel<<<g1, 128, 0, stream>>>(u, states, f_logA, f_B, f_C, f_logdt,
                                           b_logA, b_B, b_C, b_logdt);
    scan_s2_kernel<<<1, 512, 0, stream>>>(states, carries, f_logA, f_B, f_C, f_logdt,
                                          b_logA, b_B, b_C, b_logdt);
    scan_s3_kernel<<<g1, 128, 0, stream>>>(u, carries, ybuf, f_logA, f_B, f_C, f_logdt,
                                           b_logA, b_B, b_C, b_logdt);
  }
  // 7. SSM out-proj + gate: ybuf @ Wy^T * gate -> bufA (bf16)  [Kt=128 = 2 K-tiles]
  {
    dim3 g(D_DIM / 256, M_TOK / 256);
    gemm256_kernel<2, unsigned short><<<g, 512, 0, stream>>>(
        ybuf, Wy, nullptr, bufA, M_TOK, D_DIM, 128, gate, nullptr);
  }
  // 8. out_linear + residual: bufA @ w_out^T + out_b + T -> out (f32)
  {
    dim3 g(D_DIM / 256, M_TOK / 256);
    gemm256_kernel<3, float><<<g, 512, 0, stream>>>(
        bufA, w_out, out_b, out, M_TOK, D_DIM, D_DIM, T, nullptr);
  }
}

// Round 3
// 674.575 us; speedup vs baseline: 1.1028x; 1.1028x over previous
//
#include <hip/hip_runtime.h>
#include <cstdint>

// ViMBlock bf16-MFMA + chunked parallel scan. B=4, L=4096, D=1024, N=64, K=3.
// R7: 256x256 2-phase GEMM (m230/m248-verified quadrant: ~666-682 TF @ K=1024).
// BK=64 double-buffered LDS (128 KiB), 512 thr (8 waves 2Mx4N), 64 MFMA per
// wave per barrier, stage(t+1) issued before compute(t), ONE __syncthreads
// per K-tile (implicit vmcnt(0) drain after full compute phase).
// Keeps R6's verified conflict-free LDS swizzle (BANK_CONFLICT=0) and
// XCD-chunked block swizzle (FETCH 137->63MB). No sched_barrier pinning.
// u-proj (N=128) stays on the 128^2 2-phase kernel.

#define L_SEQ 4096
#define D_DIM 1024
#define B_SZ 4
#define M_TOK (B_SZ * L_SEQ)   // 16384 tokens
#define CHUNKS 64
#define CLEN (L_SEQ / CHUNKS)  // 64

typedef short bf16x8 __attribute__((ext_vector_type(8)));
typedef float floatx4 __attribute__((ext_vector_type(4)));

__device__ inline unsigned short f2bf(float f) {
  union { float f; unsigned int u; } v; v.f = f;
  unsigned int r = v.u + 0x7FFFu + ((v.u >> 16) & 1u);
  return (unsigned short)(r >> 16);
}
__device__ inline float bf2f(unsigned short h) {
  union { unsigned int u; float f; } v; v.u = ((unsigned int)h) << 16;
  return v.f;
}

__device__ inline void load_lds16(const unsigned short* g, unsigned short* l) {
  __builtin_amdgcn_global_load_lds(
      (const __attribute__((address_space(1))) unsigned int*)g,
      (__attribute__((address_space(3))) unsigned int*)l, 16, 0, 0);
}

// ---------------- RMSNorm: fp32 in -> bf16 out ----------------
__global__ __launch_bounds__(256) void rmsnorm_kernel(
    const float* __restrict__ T, const float* __restrict__ scale,
    unsigned short* __restrict__ Tn) {
  int tok = blockIdx.x;
  int t = threadIdx.x;
  const float4* row = (const float4*)(T + (size_t)tok * D_DIM);
  float4 v = row[t];
  float ss = v.x*v.x + v.y*v.y + v.z*v.z + v.w*v.w;
  #pragma unroll
  for (int off = 32; off > 0; off >>= 1) ss += __shfl_down(ss, off);
  __shared__ float part[4];
  if ((t & 63) == 0) part[t >> 6] = ss;
  __syncthreads();
  float total = part[0] + part[1] + part[2] + part[3];
  float rinv = rsqrtf(total * (1.0f / D_DIM) + 1e-6f);
  const float4* sc4 = (const float4*)scale;
  float4 s = sc4[t];
  ushort4 o;
  o.x = f2bf(v.x * rinv * s.x); o.y = f2bf(v.y * rinv * s.y);
  o.z = f2bf(v.z * rinv * s.z); o.w = f2bf(v.w * rinv * s.w);
  ((ushort4*)(Tn + (size_t)tok * D_DIM))[t] = o;
}

// ---------------- fp32 -> bf16 convert ----------------
__global__ __launch_bounds__(256) void f2bf_vec_kernel(
    const float* __restrict__ in, unsigned short* __restrict__ out, int n4) {
  int i = blockIdx.x * 256 + threadIdx.x;
  if (i < n4) {
    float4 v = ((const float4*)in)[i];
    ushort4 o; o.x = f2bf(v.x); o.y = f2bf(v.y); o.z = f2bf(v.z); o.w = f2bf(v.w);
    ((ushort4*)out)[i] = o;
  }
}

// ---------------- prepack SSM weights -> bf16 ----------------
__global__ void prepack_kernel(
    const float* __restrict__ f_win, const float* __restrict__ b_win,
    const float* __restrict__ f_wout, const float* __restrict__ b_wout,
    unsigned short* __restrict__ Wu, unsigned short* __restrict__ Wy) {
  int i = blockIdx.x * blockDim.x + threadIdx.x;
  if (i < 128 * D_DIM) {
    int n = i >> 10, k = i & (D_DIM - 1);
    Wu[i] = f2bf((n < 64) ? f_win[n * D_DIM + k] : b_win[(n - 64) * D_DIM + k]);
    int d = i >> 7, kk = i & 127;
    Wy[i] = f2bf((kk < 64) ? f_wout[d * 64 + kk] : b_wout[d * 64 + (kk - 64)]);
  }
}

// ================= 256x256 2-phase MFMA GEMM: C = A @ Bw^T =================
// 512 threads = 8 waves, wave grid 2(M) x 4(N); per-wave 128x64 output
// (acc[8][4] f32x4). LDS: dbuf x [256][64] bf16 per operand = 128 KiB.
// LDS swizzle (verified R6, BANK_CONFLICT=0): element (row r, k-chunk c)
// stored at 16B-slot ((c + r) & 7) within its row; linear gload_lds dest
// with pre-permuted per-lane global source; same perm on ds_read addrs.
// Loop: stage(t+1) -> compute(t): 2 x {12 ds_read_b128, 32 MFMA} ->
// __syncthreads (single drain point per K-tile).
// MODE semantics identical to gemm_mfma_kernel.
template<int MODE, typename OUT_T>
__global__ __launch_bounds__(512, 2) void gemm256_kernel(
    const unsigned short* __restrict__ A, const unsigned short* __restrict__ Bw,
    const float* __restrict__ bias, OUT_T* __restrict__ out,
    int M, int N, int Kt,
    const void* __restrict__ aux0, unsigned short* __restrict__ aux1) {
  __shared__ __align__(16) unsigned short As2[2][256 * 64];
  __shared__ __align__(16) unsigned short Bs2[2][256 * 64];
  const int tid = threadIdx.x;
  const int w = tid >> 6, lane = tid & 63;
  const int quad = lane >> 4, lrow = lane & 15;
  const int wm = w >> 2, wn = w & 3;

  // T1: XCD-aware chunked swizzle (launch shapes guarantee nwg % 8 == 0)
  const int nx = N >> 8;
  const int nwg = nx * (M >> 8);
  int obid = blockIdx.y * nx + blockIdx.x;
  int swz = (nwg & 7) ? obid : ((obid & 7) * (nwg >> 3) + (obid >> 3));
  const int bm = (swz / nx) << 8;
  const int bn = (swz % nx) << 8;

  // per-lane stage source offset (elements): inverse LDS-slot permutation.
  const int lr = lane >> 3, ls = lane & 7;
  const int laneOff = lr * Kt + (((ls - lr) & 7) << 3);
  const unsigned short* Asrc = A + (size_t)bm * Kt + laneOff;
  const unsigned short* Bsrc = Bw + (size_t)bn * Kt + laneOff;

  floatx4 acc[8][4] = {};
  const int nkt = Kt >> 6;      // # K-tiles of 64

  auto stageTile = [&](int buf, int kt) {
    // A: 8 waves x 4 instrs cover 256 rows (8 rows per instr)
    #pragma unroll
    for (int j = 0; j < 4; ++j) {
      int t0 = j * 64 + w * 8;
      load_lds16(Asrc + (size_t)t0 * Kt + kt * 64, &As2[buf][t0 * 64]);
    }
    #pragma unroll
    for (int j = 0; j < 4; ++j) {
      int t0 = j * 64 + w * 8;
      load_lds16(Bsrc + (size_t)t0 * Kt + kt * 64, &Bs2[buf][t0 * 64]);
    }
  };
  // fragment LDS address (elements): row r, k-half ks, this lane's quad
  auto fragAddr = [&](int r, int ks) {
    return (r << 6) + ((((ks << 2) + quad + r) & 7) << 3);
  };

  const int rA0 = wm * 128 + lrow;
  const int rB0 = wn * 64 + lrow;

  // prologue: stage tile 0 into buffer 0
  stageTile(0, 0);
  __syncthreads();

  int cur = 0;
  for (int t = 0; t < nkt; ++t) {
    if (t + 1 < nkt) stageTile(cur ^ 1, t + 1);  // in flight across compute
    const unsigned short* Ab = As2[cur];
    const unsigned short* Bb = Bs2[cur];
    #pragma unroll
    for (int ks = 0; ks < 2; ++ks) {
      bf16x8 af[8], bfr[4];
      #pragma unroll
      for (int mi = 0; mi < 8; ++mi)
        af[mi] = *(const bf16x8*)(Ab + fragAddr(rA0 + mi * 16, ks));
      #pragma unroll
      for (int ni = 0; ni < 4; ++ni)
        bfr[ni] = *(const bf16x8*)(Bb + fragAddr(rB0 + ni * 16, ks));
      __builtin_amdgcn_s_setprio(1);
      #pragma unroll
      for (int mi = 0; mi < 8; ++mi)
        #pragma unroll
        for (int ni = 0; ni < 4; ++ni)
          acc[mi][ni] = __builtin_amdgcn_mfma_f32_16x16x32_bf16(
              af[mi], bfr[ni], acc[mi][ni], 0, 0, 0);
      __builtin_amdgcn_s_setprio(0);
    }
    if (t + 1 < nkt) {
      __syncthreads();  // single drain: stage(t+1) landed, buf cur free
      cur ^= 1;
    }
  }

  // epilogue: C/D layout col=lane&15, row=quad*4+reg  [m89-verified]
  #pragma unroll
  for (int mi8 = 0; mi8 < 8; ++mi8) {
    #pragma unroll
    for (int ni = 0; ni < 4; ++ni) {
      #pragma unroll
      for (int r = 0; r < 4; ++r) {
        int m = bm + wm * 128 + mi8 * 16 + quad * 4 + r;
        int n = bn + wn * 64 + ni * 16 + lrow;
        float v = acc[mi8][ni][r];
        if (MODE == 0) {
          if (bias) v += bias[n];
          if (sizeof(OUT_T) == 2) out[(size_t)m * N + n] = (OUT_T)f2bf(v);
          else                    out[(size_t)m * N + n] = (OUT_T)v;
        } else if (MODE == 1) {
          if (bias) v += bias[n];
          if (n < D_DIM) ((unsigned short*)out)[(size_t)m * D_DIM + n] = f2bf(v);
          else aux1[(size_t)m * D_DIM + (n - D_DIM)] = f2bf(1.0f / (1.0f + expf(-v)));
        } else if (MODE == 2) {
          v *= bf2f(((const unsigned short*)aux0)[(size_t)m * N + n]);
          ((unsigned short*)out)[(size_t)m * N + n] = f2bf(v);
        } else {
          if (bias) v += bias[n];
          v += ((const float*)aux0)[(size_t)m * N + n];
          ((float*)out)[(size_t)m * N + n] = v;
        }
      }
    }
  }
}

// ---------------- 128x128 2-phase GEMM (kept for N=128 u-proj) ----------------
template<int MODE, typename OUT_T>
__global__ __launch_bounds__(256) void gemm_mfma_kernel(
    const unsigned short* __restrict__ A, const unsigned short* __restrict__ Bw,
    const float* __restrict__ bias, OUT_T* __restrict__ out,
    int M, int N, int Kt,
    const void* __restrict__ aux0, unsigned short* __restrict__ aux1) {
  __shared__ unsigned short As[2][128 * 32];
  __shared__ unsigned short Bs[2][128 * 32];
  int tid = threadIdx.x;
  int wave = tid >> 6, lane = tid & 63;
  int quad = lane >> 4, lrow = lane & 15;
  int bm = blockIdx.y * 128, bn = blockIdx.x * 128;
  int wm = (wave & 1) * 64, wn = (wave >> 1) * 64;

  int r0 = tid >> 2;
  int c8 = (tid & 3) * 8;
  const unsigned short* Ag0 = A  + (size_t)(bm + r0) * Kt + c8;
  const unsigned short* Ag1 = A  + (size_t)(bm + 64 + r0) * Kt + c8;
  const unsigned short* Bg0 = Bw + (size_t)(bn + r0) * Kt + c8;
  const unsigned short* Bg1 = Bw + (size_t)(bn + 64 + r0) * Kt + c8;
  int woff = wave * 512;

  floatx4 acc[4][4] = {};
  int nt = Kt >> 5;

  load_lds16(Ag0, &As[0][0] + woff);
  load_lds16(Ag1, &As[0][0] + 2048 + woff);
  load_lds16(Bg0, &Bs[0][0] + woff);
  load_lds16(Bg1, &Bs[0][0] + 2048 + woff);
  __syncthreads();

  int cur = 0;
  for (int t = 0; t < nt; ++t) {
    if (t + 1 < nt) {
      int k0 = (t + 1) << 5;
      int nb = cur ^ 1;
      load_lds16(Ag0 + k0, &As[nb][0] + woff);
      load_lds16(Ag1 + k0, &As[nb][0] + 2048 + woff);
      load_lds16(Bg0 + k0, &Bs[nb][0] + woff);
      load_lds16(Bg1 + k0, &Bs[nb][0] + 2048 + woff);
    }
    {
      const unsigned short* Ab = &As[cur][0];
      const unsigned short* Bb = &Bs[cur][0];
      bf16x8 af[4], bfr[4];
      #pragma unroll
      for (int mi = 0; mi < 4; ++mi)
        af[mi] = *(const bf16x8*)(Ab + (wm + mi * 16 + lrow) * 32 + quad * 8);
      #pragma unroll
      for (int ni = 0; ni < 4; ++ni)
        bfr[ni] = *(const bf16x8*)(Bb + (wn + ni * 16 + lrow) * 32 + quad * 8);
      __builtin_amdgcn_s_setprio(1);
      #pragma unroll
      for (int mi = 0; mi < 4; ++mi)
        #pragma unroll
        for (int ni = 0; ni < 4; ++ni)
          acc[mi][ni] = __builtin_amdgcn_mfma_f32_16x16x32_bf16(
              af[mi], bfr[ni], acc[mi][ni], 0, 0, 0);
      __builtin_amdgcn_s_setprio(0);
    }
    if (t + 1 < nt) {
      __syncthreads();
      cur ^= 1;
    }
  }

  #pragma unroll
  for (int mi = 0; mi < 4; ++mi) {
    #pragma unroll
    for (int ni = 0; ni < 4; ++ni) {
      #pragma unroll
      for (int r = 0; r < 4; ++r) {
        int m = bm + wm + mi * 16 + quad * 4 + r;
        int n = bn + wn + ni * 16 + lrow;
        float v = acc[mi][ni][r];
        if (MODE == 0) {
          if (bias) v += bias[n];
          if (sizeof(OUT_T) == 2) out[(size_t)m * N + n] = (OUT_T)f2bf(v);
          else                    out[(size_t)m * N + n] = (OUT_T)v;
        } else if (MODE == 1) {
          if (bias) v += bias[n];
          if (n < D_DIM) ((unsigned short*)out)[(size_t)m * D_DIM + n] = f2bf(v);
          else aux1[(size_t)m * D_DIM + (n - D_DIM)] = f2bf(1.0f / (1.0f + expf(-v)));
        } else if (MODE == 2) {
          v *= bf2f(((const unsigned short*)aux0)[(size_t)m * N + n]);
          ((unsigned short*)out)[(size_t)m * N + n] = f2bf(v);
        } else {
          if (bias) v += bias[n];
          v += ((const float*)aux0)[(size_t)m * N + n];
          ((float*)out)[(size_t)m * N + n] = v;
        }
      }
    }
  }
}

// ---------------- depthwise conv1d K=3 ----------------
__global__ __launch_bounds__(256) void dwconv_kernel(
    const unsigned short* __restrict__ x, const float* __restrict__ w,
    const float* __restrict__ b, unsigned short* __restrict__ out) {
  size_t i8 = (size_t)blockIdx.x * 256 + threadIdx.x;
  int d8 = (int)(i8 & (D_DIM / 8 - 1));
  size_t tok = i8 >> 7;
  int l = (int)(tok & (L_SEQ - 1));
  int d0 = d8 * 8;
  size_t base = tok * D_DIM + d0;
  bf16x8 cur = *(const bf16x8*)(x + base);
  float acc[8];
  #pragma unroll
  for (int j = 0; j < 8; ++j) {
    int d = d0 + j;
    acc[j] = b[d] + w[d * 3 + 1] * bf2f((unsigned short)cur[j]);
  }
  if (l > 0) {
    bf16x8 prv = *(const bf16x8*)(x + base - D_DIM);
    #pragma unroll
    for (int j = 0; j < 8; ++j) acc[j] += w[(d0 + j) * 3 + 0] * bf2f((unsigned short)prv[j]);
  }
  if (l < L_SEQ - 1) {
    bf16x8 nxt = *(const bf16x8*)(x + base + D_DIM);
    #pragma unroll
    for (int j = 0; j < 8; ++j) acc[j] += w[(d0 + j) * 3 + 2] * bf2f((unsigned short)nxt[j]);
  }
  bf16x8 o;
  #pragma unroll
  for (int j = 0; j < 8; ++j) o[j] = (short)f2bf(acc[j]);
  *(bf16x8*)(out + base) = o;
}

// ---------------- SSM params helper ----------------
__device__ inline void ssm_params(
    int col,
    const float* f_logA, const float* f_B, const float* f_C, const float* f_logdt,
    const float* b_logA, const float* b_B, const float* b_C, const float* b_logdt,
    float& Abar, float& Bbar, float& Cc, float& Aa, float& dt) {
  int dir = col >> 6, n = col & 63;
  const float* logA  = dir ? b_logA  : f_logA;
  const float* Bp    = dir ? b_B     : f_B;
  const float* Cp    = dir ? b_C     : f_C;
  const float* logdt = dir ? b_logdt : f_logdt;
  dt = expf(logdt[0]);
  Aa = -expf(logA[n]);
  Abar = expf(Aa * dt);
  float frac = (fabsf(Aa) < 1e-6f) ? dt : (Abar - 1.0f) / Aa;
  Bbar = frac * Bp[n];
  Cc = Cp[n];
}

// ---------------- scan S1: per-chunk local end-states ----------------
__global__ __launch_bounds__(128) void scan_s1_kernel(
    const float* __restrict__ u, float* __restrict__ states,
    const float* __restrict__ f_logA, const float* __restrict__ f_B,
    const float* __restrict__ f_C, const float* __restrict__ f_logdt,
    const float* __restrict__ b_logA, const float* __restrict__ b_B,
    const float* __restrict__ b_C, const float* __restrict__ b_logdt) {
  int col = threadIdx.x;
  int chunk = blockIdx.x, b = blockIdx.y;
  float Abar, Bbar, Cc, Aa, dt;
  ssm_params(col, f_logA, f_B, f_C, f_logdt, b_logA, b_B, b_C, b_logdt,
             Abar, Bbar, Cc, Aa, dt);
  size_t base = ((size_t)b * L_SEQ + (size_t)chunk * CLEN) * 128 + col;
  float h = 0.0f;
  if (col < 64) {
    for (int i0 = 0; i0 < CLEN; i0 += 8) {
      float uv[8];
      #pragma unroll
      for (int j = 0; j < 8; ++j) uv[j] = u[base + (size_t)(i0 + j) * 128];
      #pragma unroll
      for (int j = 0; j < 8; ++j) h = h * Abar + uv[j] * Bbar;
    }
  } else {
    for (int i0 = CLEN - 1; i0 >= 0; i0 -= 8) {
      float uv[8];
      #pragma unroll
      for (int j = 0; j < 8; ++j) uv[j] = u[base + (size_t)(i0 - j) * 128];
      #pragma unroll
      for (int j = 0; j < 8; ++j) h = h * Abar + uv[j] * Bbar;
    }
  }
  states[((size_t)b * CHUNKS + chunk) * 128 + col] = h;
}

// ---------------- scan S2: carries across chunks ----------------
__global__ __launch_bounds__(512) void scan_s2_kernel(
    const float* __restrict__ states, float* __restrict__ carries,
    const float* __restrict__ f_logA, const float* __restrict__ f_B,
    const float* __restrict__ f_C, const float* __restrict__ f_logdt,
    const float* __restrict__ b_logA, const float* __restrict__ b_B,
    const float* __restrict__ b_C, const float* __restrict__ b_logdt) {
  int tid = threadIdx.x;
  int b = tid >> 7, col = tid & 127;
  float Abar, Bbar, Cc, Aa, dt;
  ssm_params(col, f_logA, f_B, f_C, f_logdt, b_logA, b_B, b_C, b_logdt,
             Abar, Bbar, Cc, Aa, dt);
  float Ac = expf(Aa * dt * (float)CLEN);   // Abar^CLEN
  size_t sb = (size_t)b * CHUNKS * 128 + col;
  float cur = 0.0f;
  if (col < 64) {
    for (int c = 0; c < CHUNKS; ++c) {
      carries[sb + (size_t)c * 128] = cur;
      cur = cur * Ac + states[sb + (size_t)c * 128];
    }
  } else {
    for (int c = CHUNKS - 1; c >= 0; --c) {
      carries[sb + (size_t)c * 128] = cur;
      cur = cur * Ac + states[sb + (size_t)c * 128];
    }
  }
}

// ---------------- scan S3: re-scan with carry, write y (bf16) ----------------
__global__ __launch_bounds__(128) void scan_s3_kernel(
    const float* __restrict__ u, const float* __restrict__ carries,
    unsigned short* __restrict__ y,
    const float* __restrict__ f_logA, const float* __restrict__ f_B,
    const float* __restrict__ f_C, const float* __restrict__ f_logdt,
    const float* __restrict__ b_logA, const float* __restrict__ b_B,
    const float* __restrict__ b_C, const float* __restrict__ b_logdt) {
  int col = threadIdx.x;
  int chunk = blockIdx.x, b = blockIdx.y;
  float Abar, Bbar, Cc, Aa, dt;
  ssm_params(col, f_logA, f_B, f_C, f_logdt, b_logA, b_B, b_C, b_logdt,
             Abar, Bbar, Cc, Aa, dt);
  size_t base = ((size_t)b * L_SEQ + (size_t)chunk * CLEN) * 128 + col;
  float h = carries[((size_t)b * CHUNKS + chunk) * 128 + col];
  if (col < 64) {
    for (int i0 = 0; i0 < CLEN; i0 += 8) {
      float uv[8];
      #pragma unroll
      for (int j = 0; j < 8; ++j) uv[j] = u[base + (size_t)(i0 + j) * 128];
      #pragma unroll
      for (int j = 0; j < 8; ++j) {
        h = h * Abar + uv[j] * Bbar;
        y[base + (size_t)(i0 + j) * 128] = f2bf(h * Cc);
      }
    }
  } else {
    for (int i0 = CLEN - 1; i0 >= 0; i0 -= 8) {
      float uv[8];
      #pragma unroll
      for (int j = 0; j < 8; ++j) uv[j] = u[base + (size_t)(i0 - j) * 128];
      #pragma unroll
      for (int j = 0; j < 8; ++j) {
        h = h * Abar + uv[j] * Bbar;
        y[base + (size_t)(i0 - j) * 128] = f2bf(h * Cc);
      }
    }
  }
}

extern "C" void kernel_launch(void* const* d_in, const int* in_sizes, int n_in,
                              void* d_out, int out_size, void* d_ws, size_t ws_size,
                              hipStream_t stream) {
  const float* T         = (const float*)d_in[0];
  const float* norm_scale= (const float*)d_in[1];
  const float* in_w      = (const float*)d_in[2];
  const float* in_b      = (const float*)d_in[3];
  const float* dw_w      = (const float*)d_in[4];
  const float* dw_b      = (const float*)d_in[5];
  const float* pw_w      = (const float*)d_in[6];
  const float* pw_b      = (const float*)d_in[7];
  const float* f_win     = (const float*)d_in[8];
  const float* f_wout    = (const float*)d_in[9];
  const float* f_logA    = (const float*)d_in[10];
  const float* f_B       = (const float*)d_in[11];
  const float* f_C       = (const float*)d_in[12];
  const float* f_logdt   = (const float*)d_in[13];
  const float* b_win     = (const float*)d_in[14];
  const float* b_wout    = (const float*)d_in[15];
  const float* b_logA    = (const float*)d_in[16];
  const float* b_B       = (const float*)d_in[17];
  const float* b_C       = (const float*)d_in[18];
  const float* b_logdt   = (const float*)d_in[19];
  const float* out_w     = (const float*)d_in[20];
  const float* out_b     = (const float*)d_in[21];
  float* out = (float*)d_out;

  char* ws = (char*)d_ws;
  const size_t MD = (size_t)M_TOK * D_DIM;
  unsigned short* gate  = (unsigned short*)ws;              ws += MD * 2;
  unsigned short* bufA  = (unsigned short*)ws;              ws += MD * 2;
  unsigned short* bufB  = (unsigned short*)ws;              ws += MD * 2;
  float*          u     = (float*)ws;                       ws += (size_t)M_TOK * 128 * 4;
  unsigned short* ybuf  = (unsigned short*)ws;              ws += (size_t)M_TOK * 128 * 2;
  unsigned short* w_in  = (unsigned short*)ws;              ws += (size_t)2 * D_DIM * D_DIM * 2;
  unsigned short* w_pw  = (unsigned short*)ws;              ws += (size_t)D_DIM * D_DIM * 2;
  unsigned short* w_out = (unsigned short*)ws;              ws += (size_t)D_DIM * D_DIM * 2;
  unsigned short* Wu    = (unsigned short*)ws;              ws += (size_t)128 * D_DIM * 2;
  unsigned short* Wy    = (unsigned short*)ws;              ws += (size_t)128 * D_DIM * 2;
  float*          states= (float*)ws;                       ws += (size_t)B_SZ * CHUNKS * 128 * 4;
  float*          carries=(float*)ws;

  // 0. weight conversion / prepack
  f2bf_vec_kernel<<<(2 * D_DIM * D_DIM / 4 + 255) / 256, 256, 0, stream>>>(in_w, w_in, 2 * D_DIM * D_DIM / 4);
  f2bf_vec_kernel<<<(D_DIM * D_DIM / 4 + 255) / 256, 256, 0, stream>>>(pw_w, w_pw, D_DIM * D_DIM / 4);
  f2bf_vec_kernel<<<(D_DIM * D_DIM / 4 + 255) / 256, 256, 0, stream>>>(out_w, w_out, D_DIM * D_DIM / 4);
  prepack_kernel<<<(128 * D_DIM) / 256, 256, 0, stream>>>(f_win, b_win, f_wout, b_wout, Wu, Wy);
  // 1. RMSNorm: T -> bufA (bf16)
  rmsnorm_kernel<<<M_TOK, 256, 0, stream>>>(T, norm_scale, bufA);
  // 2. in_linear: bufA @ w_in^T + in_b -> x(bufB bf16), gate(bf16)
  {
    dim3 g((2 * D_DIM) / 256, M_TOK / 256);
    gemm256_kernel<1, unsigned short><<<g, 512, 0, stream>>>(
        bufA, w_in, in_b, bufB, M_TOK, 2 * D_DIM, D_DIM, nullptr, gate);
  }
  // 3. depthwise conv: bufB -> bufA
  dwconv_kernel<<<(MD / 8) / 256, 256, 0, stream>>>(bufB, dw_w, dw_b, bufA);
  // 4. pointwise: bufA @ w_pw^T + pw_b -> bufB (x_conv bf16)
  {
    dim3 g(D_DIM / 256, M_TOK / 256);
    gemm256_kernel<0, unsigned short><<<g, 512, 0, stream>>>(
        bufA, w_pw, pw_b, bufB, M_TOK, D_DIM, D_DIM, nullptr, nullptr);
  }
  // 5. SSM in-proj: bufB @ Wu^T -> u (f32, M x 128)  [128^2 kernel]
  {
    dim3 g(1, M_TOK / 128);
    gemm_mfma_kernel<0, float><<<g, 256, 0, stream>>>(
        bufB, Wu, nullptr, u, M_TOK, 128, D_DIM, nullptr, nullptr);
  }
  // 6. chunked bidirectional scan: u -> ybuf (bf16)
  {
    dim3 g1(CHUNKS, B_SZ);
    scan_s1_kernel<<<g1, 128, 0, stream>>>(u, states, f_logA, f_B, f_C, f_logdt,
                                           b_logA, b_B, b_C, b_logdt);
    scan_s2_kernel<<<1, 512, 0, stream>>>(states, carries, f_logA, f_B, f_C, f_logdt,
                                          b_logA, b_B, b_C, b_logdt);
    scan_s3_kernel<<<g1, 128, 0, stream>>>(u, carries, ybuf, f_logA, f_B, f_C, f_logdt,
                                           b_logA, b_B, b_C, b_logdt);
  }
  // 7. SSM out-proj + gate: ybuf @ Wy^T * gate -> bufA (bf16)  [Kt=128 = 2 K-tiles]
  {
    dim3 g(D_DIM / 256, M_TOK / 256);
    gemm256_kernel<2, unsigned short><<<g, 512, 0, stream>>>(
        ybuf, Wy, nullptr, bufA, M_TOK, D_DIM, 128, gate, nullptr);
  }
  // 8. out_linear + residual: bufA @ w_out^T + out_b + T -> out (f32)
  {
    dim3 g(D_DIM / 256, M_TOK / 256);
    gemm256_kernel<3, float><<<g, 512, 0, stream>>>(
        bufA, w_out, out_b, out, M_TOK, D_DIM, D_DIM, T, nullptr);
  }
}